// Round 1
// baseline (55.222 us; speedup 1.0000x reference)
//
#include <hip/hip_runtime.h>
#include <math.h>

namespace {
constexpr int kNB  = 16;
constexpr int kNF  = 512;
constexpr int kNTS = 2048;
constexpr int kTPB = 256;
constexpr int kEPT = kNTS / kTPB;  // 8 elements per thread
// 1/(8*pi^2), rounded to fp32 (matches numpy float32 scalar cast)
constexpr float kC     = 0.012665147955292222f;
constexpr float kTwoPi = 6.28318530717958647692f;
}

__launch_bounds__(kTPB)
__global__ void wavelet_ls_kernel(const float* __restrict__ ys,
                                  const float* __restrict__ ts,
                                  const float* __restrict__ freq,
                                  float* __restrict__ out) {
  const int f    = blockIdx.x;   // frequency index
  const int b    = blockIdx.y;   // batch index
  const int tid  = threadIdx.x;
  const int lane = tid & 63;
  const int wave = tid >> 6;

  const float* __restrict__ tsb = ts + b * kNTS;
  const float* __restrict__ ysb = ys + b * kNTS;

  // tau = 0.5*(ts[b, NTS/2] + ts[b, NTS/2+1])
  const float tau   = 0.5f * (tsb[kNTS / 2] + tsb[kNTS / 2 + 1]);
  const float omega = freq[f] * kTwoPi;

  // Per-thread sample state kept in registers across both passes.
  float tv[kEPT], yv[kEPT], wv[kEPT];

  // Pass-1 accumulators: sum_w, w*sin, w*cos, w*sin*cos, w*sin^2, w*cos^2, w*y
  float acc[7];
#pragma unroll
  for (int i = 0; i < 7; ++i) acc[i] = 0.0f;

#pragma unroll
  for (int k = 0; k < kEPT; ++k) {
    const int idx = k * kTPB + tid;   // coalesced
    const float t = tsb[idx];
    const float y = ysb[idx];
    tv[k] = t;
    yv[k] = y;
    const float dz = omega * (t - tau);
    const float e  = (-kC * dz) * dz;       // matches ref: (-C * dz) * dz
    const float w  = expf(e);
    wv[k] = w;
    float sn, cs;
    sincosf(omega * t, &sn, &cs);           // theta = omega * t (fp32), accurate sincos
    acc[0] += w;
    acc[1] += w * sn;
    acc[2] += w * cs;
    acc[3] += w * (sn * cs);
    acc[4] += w * (sn * sn);
    acc[5] += w * (cs * cs);
    acc[6] += w * y;
  }

  __shared__ float lds1[4][7];
#pragma unroll
  for (int i = 0; i < 7; ++i) {
    float v = acc[i];
#pragma unroll
    for (int off = 32; off > 0; off >>= 1) v += __shfl_down(v, off, 64);
    if (lane == 0) lds1[wave][i] = v;
  }
  __syncthreads();

  // All threads compute totals + scalar intermediates redundantly (no extra time).
  float tot[7];
#pragma unroll
  for (int i = 0; i < 7; ++i)
    tot[i] = lds1[0][i] + lds1[1][i] + lds1[2][i] + lds1[3][i];

  const float sum_w   = tot[0];
  const float sin_one = tot[1] / sum_w;
  const float cos_one = tot[2] / sum_w;
  const float sin_cos = tot[3] / sum_w;
  const float sin_sin = tot[4] / sum_w;
  const float cos_cos = tot[5] / sum_w;
  const float ys_one  = tot[6] / sum_w;

  const float num = 2.0f * (sin_cos - sin_one * cos_one);
  const float den = (cos_cos - cos_one * cos_one) - (sin_sin - sin_one * sin_one);
  const float time_shift = atan2f(num, den) / (2.0f * omega);

  // Pass 2: sincos(omega*(t - time_shift)) with the SAME rounding structure as ref.
  float acc2[4];
#pragma unroll
  for (int i = 0; i < 4; ++i) acc2[i] = 0.0f;

#pragma unroll
  for (int k = 0; k < kEPT; ++k) {
    float sn, cs;
    sincosf(omega * (tv[k] - time_shift), &sn, &cs);
    const float w = wv[k];
    acc2[0] += w * cs;            // -> cos_shift_one
    acc2[1] += w * sn;            // -> sin_shift_one
    acc2[2] += w * (yv[k] * cs);  // -> ys_cos_shift
    acc2[3] += w * (yv[k] * sn);  // -> ys_sin_shift
  }

  __shared__ float lds2[4][4];
#pragma unroll
  for (int i = 0; i < 4; ++i) {
    float v = acc2[i];
#pragma unroll
    for (int off = 32; off > 0; off >>= 1) v += __shfl_down(v, off, 64);
    if (lane == 0) lds2[wave][i] = v;
  }
  __syncthreads();

  if (tid == 0) {
    float t2[4];
#pragma unroll
    for (int i = 0; i < 4; ++i)
      t2[i] = lds2[0][i] + lds2[1][i] + lds2[2][i] + lds2[3][i];

    const float cos_shift_one = t2[0] / sum_w;
    const float sin_shift_one = t2[1] / sum_w;
    const float ys_cos_shift  = t2[2] / sum_w;
    const float ys_sin_shift  = t2[3] / sum_w;

    float stc, ctc;
    sincosf(omega * (time_shift - tau), &stc, &ctc);

    const float A  = 2.0f * (ys_cos_shift - ys_one * cos_shift_one);
    const float B  = 2.0f * (ys_sin_shift - ys_one * sin_shift_one);
    const float a0 = ys_one;
    const float a1 = ctc * A - stc * B;
    const float a2 = stc * A + ctc * B;
    const float wwp   = a1 * a1 + a2 * a2;
    const float phase = atan2f(a2, a1);

    const int o = b * kNF + f;
    out[0 * kNB * kNF + o] = wwp;
    out[1 * kNB * kNF + o] = phase;
    out[2 * kNB * kNF + o] = a0;
    out[3 * kNB * kNF + o] = a1;
    out[4 * kNB * kNF + o] = a2;
  }
}

extern "C" void kernel_launch(void* const* d_in, const int* in_sizes, int n_in,
                              void* d_out, int out_size, void* d_ws, size_t ws_size,
                              hipStream_t stream) {
  const float* ys   = (const float*)d_in[0];
  const float* ts   = (const float*)d_in[1];
  const float* freq = (const float*)d_in[2];
  float* out = (float*)d_out;

  dim3 grid(kNF, kNB);
  wavelet_ls_kernel<<<grid, kTPB, 0, stream>>>(ys, ts, freq, out);
}

// Round 2
// 43.270 us; speedup vs baseline: 1.2762x; 1.2762x over previous
//
#include <hip/hip_runtime.h>
#include <math.h>

namespace {
constexpr int kNB  = 16;
constexpr int kNF  = 512;
constexpr int kNTS = 2048;
constexpr int kTPB = 128;
constexpr int kEPT = kNTS / kTPB;   // 16 elements per thread
constexpr int kVPT = kEPT / 4;      // 4 float4 loads per array
// 1/(8*pi^2) rounded to fp32
constexpr float kC     = 0.012665147955292222f;
constexpr float kTwoPi = 6.28318530717958647692f;
}

// Branchless sincos for |x| < 2^17 (our args are bounded by ~1.3e5).
// fp32 Cody-Waite reduction mod pi/2 with 7-bit chunks (k*ci exact since k<2^17),
// then Cephes minimax polys. Total error ~2-3e-7 abs.
__device__ __forceinline__ void fast_sincosf(float x, float& s_out, float& c_out) {
  constexpr float kTwoOverPi = 0.636619772367581343f;
  constexpr float kP1 = 1.5703125f;               // 201 * 2^-7
  constexpr float kP2 = 4.84466552734375e-4f;     // 127 * 2^-18
  constexpr float kP3 = -6.407499313354492e-7f;   // -86 * 2^-27
  constexpr float kP4 = 9.895302355289459e-10f;   //  68 * 2^-36
  constexpr float kP5 = 2.5579538487363607e-12f;  //  90 * 2^-45

  float kf = rintf(x * kTwoOverPi);
  int   q  = (int)kf;
  float r  = fmaf(-kf, kP1, x);
  r = fmaf(-kf, kP2, r);
  r = fmaf(-kf, kP3, r);
  r = fmaf(-kf, kP4, r);
  r = fmaf(-kf, kP5, r);

  float z = r * r;
  // sin(r), |r| <= pi/4 + eps
  float sp = fmaf(fmaf(-1.9515295891e-4f, z, 8.3321608736e-3f), z, -1.6666654611e-1f);
  float s  = fmaf(sp * z, r, r);
  // cos(r)
  float cp = fmaf(fmaf(2.443315711809948e-5f, z, -1.388731625493765e-3f), z,
                  4.166664568298827e-2f);
  float c  = fmaf(cp, z * z, fmaf(-0.5f, z, 1.0f));

  // quadrant fixup: q&3 selects {s,c,-s,-c} / {c,-s,-c,s}
  bool sw = (q & 1) != 0;
  float ss = sw ? c : s;
  float cc = sw ? s : c;
  unsigned sgn_s = (unsigned)(q & 2) << 30;
  unsigned sgn_c = (unsigned)((q + 1) & 2) << 30;
  s_out = __uint_as_float(__float_as_uint(ss) ^ sgn_s);
  c_out = __uint_as_float(__float_as_uint(cc) ^ sgn_c);
}

__launch_bounds__(kTPB)
__global__ void wavelet_ls_kernel(const float* __restrict__ ys,
                                  const float* __restrict__ ts,
                                  const float* __restrict__ freq,
                                  float* __restrict__ out) {
  const int f    = blockIdx.x;   // frequency index
  const int b    = blockIdx.y;   // batch index
  const int tid  = threadIdx.x;
  const int wave = tid >> 6;

  const float* __restrict__ tsb = ts + b * kNTS;
  const float* __restrict__ ysb = ys + b * kNTS;
  const float4* __restrict__ ts4 = (const float4*)tsb;
  const float4* __restrict__ ys4 = (const float4*)ysb;

  const float tau   = 0.5f * (tsb[kNTS / 2] + tsb[kNTS / 2 + 1]);
  const float omega = freq[f] * kTwoPi;

  // Per-thread sample state kept in registers across both passes.
  float tv[kEPT], yv[kEPT], wv[kEPT];

  // Pass-1 accumulators: sum_w, w*sin, w*cos, w*sin*cos, w*sin^2, w*cos^2, w*y
  float acc[7];
#pragma unroll
  for (int i = 0; i < 7; ++i) acc[i] = 0.0f;

#pragma unroll
  for (int v = 0; v < kVPT; ++v) {
    const int vidx = v * kTPB + tid;      // coalesced float4
    const float4 t4 = ts4[vidx];
    const float4 y4 = ys4[vidx];
    tv[v * 4 + 0] = t4.x; tv[v * 4 + 1] = t4.y; tv[v * 4 + 2] = t4.z; tv[v * 4 + 3] = t4.w;
    yv[v * 4 + 0] = y4.x; yv[v * 4 + 1] = y4.y; yv[v * 4 + 2] = y4.z; yv[v * 4 + 3] = y4.w;
  }

#pragma unroll
  for (int k = 0; k < kEPT; ++k) {
    const float t = tv[k];
    const float y = yv[k];
    const float dz = omega * (t - tau);        // same rounding structure as ref
    const float e  = (-kC * dz) * dz;
    const float w  = __expf(e);
    wv[k] = w;
    float sn, cs;
    fast_sincosf(omega * t, sn, cs);
    acc[0] += w;
    acc[1] = fmaf(w, sn, acc[1]);
    acc[2] = fmaf(w, cs, acc[2]);
    acc[3] = fmaf(w, sn * cs, acc[3]);
    acc[4] = fmaf(w, sn * sn, acc[4]);
    acc[5] = fmaf(w, cs * cs, acc[5]);
    acc[6] = fmaf(w, y, acc[6]);
  }

  // Butterfly: every lane gets the wave total; then combine the 2 waves via LDS.
  __shared__ float lds1[2][7];
#pragma unroll
  for (int i = 0; i < 7; ++i) {
    float v = acc[i];
#pragma unroll
    for (int off = 1; off < 64; off <<= 1) v += __shfl_xor(v, off, 64);
    acc[i] = v;
    if ((tid & 63) == 0) lds1[wave][i] = v;
  }
  __syncthreads();

  float tot[7];
#pragma unroll
  for (int i = 0; i < 7; ++i) tot[i] = lds1[0][i] + lds1[1][i];

  const float sum_w   = tot[0];
  const float inv_w   = 1.0f / sum_w;
  const float sin_one = tot[1] * inv_w;   // NB: ref divides; mul-by-recip differs
  const float cos_one = tot[2] * inv_w;   // at ulp level only (same for all below)
  const float sin_cos = tot[3] * inv_w;
  const float sin_sin = tot[4] * inv_w;
  const float cos_cos = tot[5] * inv_w;
  const float ys_one  = tot[6] * inv_w;

  const float num = 2.0f * (sin_cos - sin_one * cos_one);
  const float den = (cos_cos - cos_one * cos_one) - (sin_sin - sin_one * sin_one);
  const float time_shift = atan2f(num, den) / (2.0f * omega);

  // Pass 2: sincos(omega*(t - time_shift)), same fp32 rounding path as ref.
  float acc2[4];
#pragma unroll
  for (int i = 0; i < 4; ++i) acc2[i] = 0.0f;

#pragma unroll
  for (int k = 0; k < kEPT; ++k) {
    float sn, cs;
    fast_sincosf(omega * (tv[k] - time_shift), sn, cs);
    const float w = wv[k];
    acc2[0] = fmaf(w, cs, acc2[0]);           // -> cos_shift_one
    acc2[1] = fmaf(w, sn, acc2[1]);           // -> sin_shift_one
    acc2[2] = fmaf(w, yv[k] * cs, acc2[2]);   // -> ys_cos_shift
    acc2[3] = fmaf(w, yv[k] * sn, acc2[3]);   // -> ys_sin_shift
  }

  __shared__ float lds2[2][4];
#pragma unroll
  for (int i = 0; i < 4; ++i) {
    float v = acc2[i];
#pragma unroll
    for (int off = 1; off < 64; off <<= 1) v += __shfl_xor(v, off, 64);
    if ((tid & 63) == 0) lds2[wave][i] = v;
  }
  __syncthreads();

  if (tid == 0) {
    float t2[4];
#pragma unroll
    for (int i = 0; i < 4; ++i) t2[i] = lds2[0][i] + lds2[1][i];

    const float cos_shift_one = t2[0] * inv_w;
    const float sin_shift_one = t2[1] * inv_w;
    const float ys_cos_shift  = t2[2] * inv_w;
    const float ys_sin_shift  = t2[3] * inv_w;

    float stc, ctc;
    sincosf(omega * (time_shift - tau), &stc, &ctc);  // per-block: keep libm

    const float A  = 2.0f * (ys_cos_shift - ys_one * cos_shift_one);
    const float B  = 2.0f * (ys_sin_shift - ys_one * sin_shift_one);
    const float a0 = ys_one;
    const float a1 = ctc * A - stc * B;
    const float a2 = stc * A + ctc * B;
    const float wwp   = a1 * a1 + a2 * a2;
    const float phase = atan2f(a2, a1);

    const int o = b * kNF + f;
    out[0 * kNB * kNF + o] = wwp;
    out[1 * kNB * kNF + o] = phase;
    out[2 * kNB * kNF + o] = a0;
    out[3 * kNB * kNF + o] = a1;
    out[4 * kNB * kNF + o] = a2;
  }
}

extern "C" void kernel_launch(void* const* d_in, const int* in_sizes, int n_in,
                              void* d_out, int out_size, void* d_ws, size_t ws_size,
                              hipStream_t stream) {
  const float* ys   = (const float*)d_in[0];
  const float* ts   = (const float*)d_in[1];
  const float* freq = (const float*)d_in[2];
  float* out = (float*)d_out;

  dim3 grid(kNF, kNB);
  wavelet_ls_kernel<<<grid, kTPB, 0, stream>>>(ys, ts, freq, out);
}

// Round 3
// 39.826 us; speedup vs baseline: 1.3866x; 1.0865x over previous
//
#include <hip/hip_runtime.h>
#include <math.h>

namespace {
constexpr int kNB  = 16;
constexpr int kNF  = 512;
constexpr int kNTS = 2048;
constexpr int kTPB = 256;
constexpr int kEPT = kNTS / kTPB;   // 8 elements per thread
constexpr int kVPT = kEPT / 4;      // 2 float4 loads per array
// 1/(8*pi^2) rounded to fp32
constexpr float kC     = 0.012665147955292222f;
constexpr float kTwoPi = 6.28318530717958647692f;
}

// Branchless sincos for |x| < 2^17 (args bounded by ~1.3e5).
// fp32 Cody-Waite reduction mod pi/2 with 7-bit chunks (k*ci exact since k<2^17),
// then Cephes minimax polys. Total error ~4e-7 abs (kP5 term dropped: k*2.56e-12
// <= 2.1e-7, negligible vs output tolerance).
__device__ __forceinline__ void fast_sincosf(float x, float& s_out, float& c_out) {
  constexpr float kTwoOverPi = 0.636619772367581343f;
  constexpr float kP1 = 1.5703125f;               // 201 * 2^-7
  constexpr float kP2 = 4.84466552734375e-4f;     // 127 * 2^-18
  constexpr float kP3 = -6.407499313354492e-7f;   // -86 * 2^-27
  constexpr float kP4 = 9.895302355289459e-10f;   //  68 * 2^-36

  float kf = rintf(x * kTwoOverPi);
  int   q  = (int)kf;
  float r  = fmaf(-kf, kP1, x);
  r = fmaf(-kf, kP2, r);
  r = fmaf(-kf, kP3, r);
  r = fmaf(-kf, kP4, r);

  float z = r * r;
  float sp = fmaf(fmaf(-1.9515295891e-4f, z, 8.3321608736e-3f), z, -1.6666654611e-1f);
  float s  = fmaf(sp * z, r, r);
  float cp = fmaf(fmaf(2.443315711809948e-5f, z, -1.388731625493765e-3f), z,
                  4.166664568298827e-2f);
  float c  = fmaf(cp, z * z, fmaf(-0.5f, z, 1.0f));

  bool sw = (q & 1) != 0;
  float ss = sw ? c : s;
  float cc = sw ? s : c;
  unsigned sgn_s = (unsigned)(q & 2) << 30;
  unsigned sgn_c = (unsigned)((q + 1) & 2) << 30;
  s_out = __uint_as_float(__float_as_uint(ss) ^ sgn_s);
  c_out = __uint_as_float(__float_as_uint(cc) ^ sgn_c);
}

__launch_bounds__(kTPB)
__global__ void wavelet_ls_kernel(const float* __restrict__ ys,
                                  const float* __restrict__ ts,
                                  const float* __restrict__ freq,
                                  float* __restrict__ out) {
  const int f    = blockIdx.x;   // frequency index
  const int b    = blockIdx.y;   // batch index
  const int tid  = threadIdx.x;
  const int wave = tid >> 6;

  const float* __restrict__ tsb = ts + b * kNTS;
  const float* __restrict__ ysb = ys + b * kNTS;
  const float4* __restrict__ ts4 = (const float4*)tsb;
  const float4* __restrict__ ys4 = (const float4*)ysb;

  const float tau   = 0.5f * (tsb[kNTS / 2] + tsb[kNTS / 2 + 1]);
  const float omega = freq[f] * kTwoPi;

  // Per-thread sample state kept in registers across both passes.
  float tv[kEPT], yv[kEPT], wv[kEPT];

#pragma unroll
  for (int v = 0; v < kVPT; ++v) {
    const int vidx = v * kTPB + tid;      // coalesced float4
    const float4 t4 = ts4[vidx];
    const float4 y4 = ys4[vidx];
    tv[v * 4 + 0] = t4.x; tv[v * 4 + 1] = t4.y; tv[v * 4 + 2] = t4.z; tv[v * 4 + 3] = t4.w;
    yv[v * 4 + 0] = y4.x; yv[v * 4 + 1] = y4.y; yv[v * 4 + 2] = y4.z; yv[v * 4 + 3] = y4.w;
  }

  // Pass-1 accumulators (6): sum_w, w*sin, w*cos, w*(sin*cos), w*(cos^2-sin^2), w*y
  // (cos^2 - sin^2 accumulated as 1 - 2*sin^2; deviation vs ref ~3e-7/elem, which
  //  enters only through atan2's angle -> uniform (a1,a2) rotation <= ~3e-4. Safe.)
  float acc[6];
#pragma unroll
  for (int i = 0; i < 6; ++i) acc[i] = 0.0f;

#pragma unroll
  for (int k = 0; k < kEPT; ++k) {
    const float t = tv[k];
    const float y = yv[k];
    const float dz = omega * (t - tau);        // same rounding structure as ref
    const float e  = (-kC * dz) * dz;
    const float w  = __expf(e);
    wv[k] = w;
    float sn, cs;
    fast_sincosf(omega * t, sn, cs);
    const float c2 = fmaf(-2.0f * sn, sn, 1.0f);   // cos^2 - sin^2 (+ ~3e-7)
    acc[0] += w;
    acc[1] = fmaf(w, sn, acc[1]);
    acc[2] = fmaf(w, cs, acc[2]);
    acc[3] = fmaf(w, sn * cs, acc[3]);
    acc[4] = fmaf(w, c2, acc[4]);
    acc[5] = fmaf(w, y, acc[5]);
  }

  // Butterfly within wave; combine the 4 waves via LDS.
  __shared__ float lds1[4][6];
#pragma unroll
  for (int i = 0; i < 6; ++i) {
    float v = acc[i];
#pragma unroll
    for (int off = 1; off < 64; off <<= 1) v += __shfl_xor(v, off, 64);
    if ((tid & 63) == 0) lds1[wave][i] = v;
  }
  __syncthreads();

  float tot[6];
#pragma unroll
  for (int i = 0; i < 6; ++i)
    tot[i] = (lds1[0][i] + lds1[1][i]) + (lds1[2][i] + lds1[3][i]);

  const float sum_w   = tot[0];
  const float inv_w   = 1.0f / sum_w;
  const float sin_one = tot[1] * inv_w;
  const float cos_one = tot[2] * inv_w;
  const float sin_cos = tot[3] * inv_w;
  const float cc_ss   = tot[4] * inv_w;    // cos_cos - sin_sin
  const float ys_one  = tot[5] * inv_w;

  const float num = 2.0f * (sin_cos - sin_one * cos_one);
  const float den = cc_ss - cos_one * cos_one + sin_one * sin_one;
  const float time_shift = atan2f(num, den) / (2.0f * omega);

  // Pass 2: recompute sincos(omega*(t - time_shift)) -- same fp32 rounding path
  // as ref. (The angle-subtraction identity is forbidden: its ~0.008 rad/elem
  // argument deviation would corrupt phase at small-amplitude bins.)
  float acc2[4];
#pragma unroll
  for (int i = 0; i < 4; ++i) acc2[i] = 0.0f;

#pragma unroll
  for (int k = 0; k < kEPT; ++k) {
    float sn, cs;
    fast_sincosf(omega * (tv[k] - time_shift), sn, cs);
    const float w = wv[k];
    acc2[0] = fmaf(w, cs, acc2[0]);           // -> cos_shift_one
    acc2[1] = fmaf(w, sn, acc2[1]);           // -> sin_shift_one
    acc2[2] = fmaf(w, yv[k] * cs, acc2[2]);   // -> ys_cos_shift
    acc2[3] = fmaf(w, yv[k] * sn, acc2[3]);   // -> ys_sin_shift
  }

  __shared__ float lds2[4][4];
#pragma unroll
  for (int i = 0; i < 4; ++i) {
    float v = acc2[i];
#pragma unroll
    for (int off = 1; off < 64; off <<= 1) v += __shfl_xor(v, off, 64);
    if ((tid & 63) == 0) lds2[wave][i] = v;
  }
  __syncthreads();

  if (tid == 0) {
    float t2[4];
#pragma unroll
    for (int i = 0; i < 4; ++i)
      t2[i] = (lds2[0][i] + lds2[1][i]) + (lds2[2][i] + lds2[3][i]);

    const float cos_shift_one = t2[0] * inv_w;
    const float sin_shift_one = t2[1] * inv_w;
    const float ys_cos_shift  = t2[2] * inv_w;
    const float ys_sin_shift  = t2[3] * inv_w;

    float stc, ctc;
    sincosf(omega * (time_shift - tau), &stc, &ctc);  // once per block: keep libm

    const float A  = 2.0f * (ys_cos_shift - ys_one * cos_shift_one);
    const float B  = 2.0f * (ys_sin_shift - ys_one * sin_shift_one);
    const float a0 = ys_one;
    const float a1 = ctc * A - stc * B;
    const float a2 = stc * A + ctc * B;
    const float wwp   = a1 * a1 + a2 * a2;
    const float phase = atan2f(a2, a1);

    const int o = b * kNF + f;
    out[0 * kNB * kNF + o] = wwp;
    out[1 * kNB * kNF + o] = phase;
    out[2 * kNB * kNF + o] = a0;
    out[3 * kNB * kNF + o] = a1;
    out[4 * kNB * kNF + o] = a2;
  }
}

extern "C" void kernel_launch(void* const* d_in, const int* in_sizes, int n_in,
                              void* d_out, int out_size, void* d_ws, size_t ws_size,
                              hipStream_t stream) {
  const float* ys   = (const float*)d_in[0];
  const float* ts   = (const float*)d_in[1];
  const float* freq = (const float*)d_in[2];
  float* out = (float*)d_out;

  dim3 grid(kNF, kNB);
  wavelet_ls_kernel<<<grid, kTPB, 0, stream>>>(ys, ts, freq, out);
}